// Round 9
// baseline (259.328 us; speedup 1.0000x reference)
//
#include <hip/hip_runtime.h>

// Problem constants
#define NPAR   8192      // parents
#define NCH    65536     // children = NPAR*8
#define RES    32
#define EPS    1e-5f

typedef __attribute__((ext_vector_type(8))) short short8;
typedef __attribute__((ext_vector_type(4))) float floatx4;

__device__ __forceinline__ unsigned short f2bf(float f) {
    union { float f; unsigned u; } v; v.f = f;
    unsigned r = v.u + 0x7fffu + ((v.u >> 16) & 1u);   // RNE
    return (unsigned short)(r >> 16);
}
__device__ __forceinline__ float bf2f(unsigned short b) {
    union { unsigned u; float f; } v; v.u = ((unsigned)b) << 16;
    return v.f;
}
// async 16B global->LDS: per-lane global addr, wave-uniform LDS base (+lane*16)
__device__ __forceinline__ void glds16(const void* g, void* l) {
    __builtin_amdgcn_global_load_lds(
        (__attribute__((address_space(1))) const void*)g,
        (__attribute__((address_space(3))) void*)l, 16, 0, 0);
}

// ---------------------------------------------------------------------------
// scatter parents into 32^3 grid (0xAA poison reads negative -> idx pass's
// bounds check rejects untouched cells). Zeroes stats[128] + zero page (512B).
__global__ void scatter_kernel(const int* __restrict__ coords, int* __restrict__ grid32,
                               float* __restrict__ stats, float* __restrict__ zpage) {
    int t = threadIdx.x;
    if (blockIdx.x == 0) {
        if (t < 128) stats[t] = 0.0f;
        else zpage[t - 128] = 0.0f;   // 128 floats = 512 B
    }
    int p = blockIdx.x * 256 + t;
    if (p < NPAR)
        grid32[(coords[p*3] << 10) + (coords[p*3+1] << 5) + coords[p*3+2]] = p;
}

// ---------------------------------------------------------------------------
// Fused prep: blocks [0,256) build idx_tab; blocks [256,688) pack weights.
// idx_tab[k][R] = input child-row for child R at tap k, or -1.
// Wp[tap][nb][ks][lane][j]: fragment-order bf16 weights (lane-linear 1KB loads).
__global__ void prep_kernel(const int* __restrict__ coords, const int* __restrict__ grid32,
                            int* __restrict__ idx_tab,
                            const float* __restrict__ W1, const float* __restrict__ W2,
                            unsigned short* __restrict__ Wp1, unsigned short* __restrict__ Wp2) {
    if (blockIdx.x < 256) {
        int R = blockIdx.x * 256 + threadIdx.x;   // 65536
        int p = R >> 3, o = R & 7;
        int bx = 2 * coords[p*3]   + ((o >> 2) & 1);
        int by = 2 * coords[p*3+1] + ((o >> 1) & 1);
        int bz = 2 * coords[p*3+2] + (o & 1);
#pragma unroll 1
        for (int k = 0; k < 27; ++k) {
            int fx = bx + k / 9 - 1, fy = by + (k / 3) % 3 - 1, fz = bz + k % 3 - 1;
            int src = -1;
            if ((unsigned)fx < 64u && (unsigned)fy < 64u && (unsigned)fz < 64u) {
                int r = grid32[((fx >> 1) << 10) + ((fy >> 1) << 5) + (fz >> 1)];
                if ((unsigned)r < (unsigned)NPAR)
                    src = r * 8 + ((fx & 1) << 2) + ((fy & 1) << 1) + (fz & 1);
            }
            idx_tab[k * NCH + R] = src;
        }
    } else {
        int idx = (blockIdx.x - 256) * 256 + threadIdx.x;   // < 110592
        int which = idx >= 55296 ? 1 : 0;
        int rem = idx - which * 55296;
        int lane = rem & 63;
        int ks   = (rem >> 6) & 3;
        int nb   = (rem >> 8) & 7;
        int tap  = rem >> 11;
        int n  = nb * 16 + (lane & 15);
        int k0 = ks * 32 + (lane >> 4) * 8;
        const float* W = which ? W2 : W1;
        unsigned short* Wp = which ? Wp2 : Wp1;
        unsigned short v[8];
#pragma unroll
        for (int j = 0; j < 8; ++j) v[j] = f2bf(W[tap * 16384 + (k0 + j) * 128 + n]);
        uint4 pk;
        pk.x = (unsigned)v[0] | ((unsigned)v[1] << 16);
        pk.y = (unsigned)v[2] | ((unsigned)v[3] << 16);
        pk.z = (unsigned)v[4] | ((unsigned)v[5] << 16);
        pk.w = (unsigned)v[6] | ((unsigned)v[7] << 16);
        *(uint4*)&Wp[(long)rem * 8] = pk;
    }
}

// ---------------------------------------------------------------------------
__global__ void gn_stats_kernel(const float* __restrict__ x, float* __restrict__ sum,
                                float* __restrict__ sq, int nrows) {
    __shared__ float s_sum[32], s_sq[32];
    int t = threadIdx.x;
    if (t < 32) { s_sum[t] = 0.0f; s_sq[t] = 0.0f; }
    __syncthreads();
    const float4* x4 = (const float4*)x;
    int total = nrows * 32;
    int idx0 = blockIdx.x * blockDim.x + t;
    int g = idx0 & 31;
    float ls = 0.0f, lq = 0.0f;
    for (int idx = idx0; idx < total; idx += gridDim.x * blockDim.x) {
        float4 v = x4[idx];
        ls += v.x + v.y + v.z + v.w;
        lq += v.x * v.x + v.y * v.y + v.z * v.z + v.w * v.w;
    }
    atomicAdd(&s_sum[g], ls);
    atomicAdd(&s_sq[g], lq);
    __syncthreads();
    if (t < 32) { atomicAdd(&sum[t], s_sum[t]); atomicAdd(&sq[t], s_sq[t]); }
}

// fp32 in -> bf16 out (GN1)
__global__ void gn_apply_kernel(const float* __restrict__ x, const float* __restrict__ sum,
                                const float* __restrict__ sq, const float* __restrict__ gamma,
                                const float* __restrict__ beta, unsigned short* __restrict__ y,
                                int nrows) {
    const float4* x4 = (const float4*)x;
    uint2* y2 = (uint2*)y;
    const float4* g4 = (const float4*)gamma;
    const float4* b4 = (const float4*)beta;
    float cnt = (float)nrows * 4.0f;
    int total = nrows * 32;
    for (int idx = blockIdx.x * blockDim.x + threadIdx.x; idx < total;
         idx += gridDim.x * blockDim.x) {
        int c4 = idx & 31;
        float mean = sum[c4] / cnt;
        float var = sq[c4] / cnt - mean * mean;
        float rstd = rsqrtf(var + EPS);
        float4 v = x4[idx];
        float4 gm = g4[c4];
        float4 bt = b4[c4];
        float a[4] = {v.x, v.y, v.z, v.w};
        float gg[4] = {gm.x, gm.y, gm.z, gm.w};
        float bb[4] = {bt.x, bt.y, bt.z, bt.w};
        unsigned short o[4];
#pragma unroll
        for (int i = 0; i < 4; ++i) {
            float tv = (a[i] - mean) * rstd * gg[i] + bb[i];
            o[i] = f2bf(tv / (1.0f + __expf(-tv)));
        }
        uint2 pk;
        pk.x = (unsigned)o[0] | ((unsigned)o[1] << 16);
        pk.y = (unsigned)o[2] | ((unsigned)o[3] << 16);
        y2[idx] = pk;
    }
}

// bf16 in -> bf16 out, in place (GN2)
__global__ void gn_apply_bf16_kernel(unsigned short* __restrict__ x,
                                     const float* __restrict__ sum, const float* __restrict__ sq,
                                     const float* __restrict__ gamma, const float* __restrict__ beta,
                                     int nrows) {
    uint2* x2 = (uint2*)x;
    const float4* g4 = (const float4*)gamma;
    const float4* b4 = (const float4*)beta;
    float cnt = (float)nrows * 4.0f;
    int total = nrows * 32;
    for (int idx = blockIdx.x * blockDim.x + threadIdx.x; idx < total;
         idx += gridDim.x * blockDim.x) {
        int c4 = idx & 31;
        float mean = sum[c4] / cnt;
        float var = sq[c4] / cnt - mean * mean;
        float rstd = rsqrtf(var + EPS);
        uint2 pk = x2[idx];
        float a[4] = {bf2f((unsigned short)(pk.x & 0xffff)), bf2f((unsigned short)(pk.x >> 16)),
                      bf2f((unsigned short)(pk.y & 0xffff)), bf2f((unsigned short)(pk.y >> 16))};
        float4 gm = g4[c4];
        float4 bt = b4[c4];
        float gg[4] = {gm.x, gm.y, gm.z, gm.w};
        float bb[4] = {bt.x, bt.y, bt.z, bt.w};
        unsigned short o[4];
#pragma unroll
        for (int i = 0; i < 4; ++i) {
            float tv = (a[i] - mean) * rstd * gg[i] + bb[i];
            o[i] = f2bf(tv / (1.0f + __expf(-tv)));
        }
        pk.x = (unsigned)o[0] | ((unsigned)o[1] << 16);
        pk.y = (unsigned)o[2] | ((unsigned)o[3] << 16);
        x2[idx] = pk;
    }
}

// ---------------------------------------------------------------------------
// MFMA conv v5: block = 64 rows, 128 threads = 2 waves; wave wv computes the
// full 64 rows x cols [wv*64, wv*64+64). Grid 1024 = 4 blocks/CU (no tail),
// LDS dbuf 2x16 KB = 32 KB -> more independent blocks per CU to overlap the
// B-L1 / A-LDS / DMA / MFMA pipes (r8 was 90% phase-serialized at 2 blocks/CU).
// A staged via async global_load_lds, fragment-order (no swizzle):
//   chunk(row,ks,quad) at shorts ((row>>4)<<11) + (ks<<9) + ((row&15)<<5) + (quad<<3)
// One glds instr = (rgrp,ks): 16 rows x contiguous 64 B -> 16 cache lines,
// LDS dst = wave-uniform base + lane*16. Invalid rows -> zeroed 512B page.
// B-frags direct from packed global Wp (lane-linear 1KB, L1-hot).
__global__ void __launch_bounds__(128) conv_mfma_kernel(
    const unsigned short* __restrict__ Ag, const unsigned short* __restrict__ Wp,
    const float* __restrict__ bias, const int* __restrict__ idx_tab,
    const float* __restrict__ resid, void* __restrict__ outp,
    const float* __restrict__ zpage, int shift, int out_bf16,
    float* __restrict__ gsum, float* __restrict__ gsq) {
    __shared__ unsigned short A_lds[2][8192];   // 2 x 16 KB

    int t = threadIdx.x;
    int R0 = blockIdx.x * 64;
    int wv = t >> 6, lane = t & 63, quad = lane >> 4, l16 = lane & 15;
    // gather roles: wave wv stages rgrp {2wv, 2wv+1}; lane = (r16, cch)
    int r16 = lane >> 2, cch = lane & 3;
    int row0 = wv * 32 + r16;          // rgrp0 = 2wv
    int row1 = wv * 32 + 16 + r16;     // rgrp1 = 2wv+1
    int base0 = (wv * 2) << 11;        // wave-uniform LDS short-offset
    int base1 = (wv * 2 + 1) << 11;
    const unsigned short* zsrc = (const unsigned short*)zpage;

    floatx4 acc[4][4];
#pragma unroll
    for (int mt = 0; mt < 4; ++mt)
#pragma unroll
        for (int nt = 0; nt < 4; ++nt)
            acc[mt][nt] = (floatx4){0.f, 0.f, 0.f, 0.f};

    // ---- prolog: tap 0 into buf 0
    int iv0 = idx_tab[R0 + row0], iv1 = idx_tab[R0 + row1];
    {
        const unsigned short* g0 = (iv0 >= 0) ? Ag + (long)(iv0 >> shift) * 128 : zsrc;
        const unsigned short* g1 = (iv1 >= 0) ? Ag + (long)(iv1 >> shift) * 128 : zsrc;
#pragma unroll
        for (int ks = 0; ks < 4; ++ks) glds16(g0 + ks * 32 + cch * 8, &A_lds[0][base0 + (ks << 9)]);
#pragma unroll
        for (int ks = 0; ks < 4; ++ks) glds16(g1 + ks * 32 + cch * 8, &A_lds[0][base1 + (ks << 9)]);
    }
    int nv0 = idx_tab[NCH + R0 + row0], nv1 = idx_tab[NCH + R0 + row1];
    __syncthreads();

#pragma unroll 1
    for (int k = 0; k < 27; ++k) {
        int cur = k & 1;
        // ---- async stage of tap k+1 into the other buffer
        if (k < 26) {
            const unsigned short* g0 = (nv0 >= 0) ? Ag + (long)(nv0 >> shift) * 128 : zsrc;
            const unsigned short* g1 = (nv1 >= 0) ? Ag + (long)(nv1 >> shift) * 128 : zsrc;
#pragma unroll
            for (int ks = 0; ks < 4; ++ks) glds16(g0 + ks * 32 + cch * 8, &A_lds[1 - cur][base0 + (ks << 9)]);
#pragma unroll
            for (int ks = 0; ks < 4; ++ks) glds16(g1 + ks * 32 + cch * 8, &A_lds[1 - cur][base1 + (ks << 9)]);
            if (k < 25) {
                nv0 = idx_tab[(k + 2) * NCH + R0 + row0];
                nv1 = idx_tab[(k + 2) * NCH + R0 + row1];
            }
        }
        // ---- dense 64x64x128 wave GEMM for tap k
#pragma unroll
        for (int ks = 0; ks < 4; ++ks) {
            short8 afr[4], bfr[4];
#pragma unroll
            for (int mt = 0; mt < 4; ++mt)
                afr[mt] = *(const short8*)&A_lds[cur][(mt << 11) + (ks << 9) + (l16 << 5) + (quad << 3)];
#pragma unroll
            for (int nt = 0; nt < 4; ++nt) {
                int cb = wv * 4 + nt;
                bfr[nt] = *(const short8*)&Wp[((((k << 3) + cb) << 2) + ks) * 512 + (lane << 3)];
            }
#pragma unroll
            for (int mt = 0; mt < 4; ++mt)
#pragma unroll
                for (int nt = 0; nt < 4; ++nt)
                    acc[mt][nt] = __builtin_amdgcn_mfma_f32_16x16x32_bf16(
                        afr[mt], bfr[nt], acc[mt][nt], 0, 0, 0);
        }
        __syncthreads();   // vmcnt(0)+barrier: k+1 staged, buf[cur] reads done
    }

    // ---- epilogue
    float s[4] = {0.f, 0.f, 0.f, 0.f}, q[4] = {0.f, 0.f, 0.f, 0.f};
#pragma unroll
    for (int nt = 0; nt < 4; ++nt) {
        int col = wv * 64 + nt * 16 + l16;
        float bv = bias[col];
#pragma unroll
        for (int mt = 0; mt < 4; ++mt) {
#pragma unroll
            for (int r = 0; r < 4; ++r) {
                int row = mt * 16 + quad * 4 + r;
                long R = (long)R0 + row;
                float v = acc[mt][nt][r] + bv;
                if (out_bf16) {
                    unsigned short u = f2bf(v);
                    ((unsigned short*)outp)[R * 128 + col] = u;
                    float vr = bf2f(u);
                    s[nt] += vr;
                    q[nt] += vr * vr;
                } else {
                    v += resid[(R >> 3) * 128 + col];
                    ((float*)outp)[R * 128 + col] = v;
                }
            }
        }
    }
    if (gsum) {
        float* sred = (float*)A_lds;   // safe: loop's trailing barrier passed
        if (t < 64) sred[t] = 0.0f;
        __syncthreads();
#pragma unroll
        for (int nt = 0; nt < 4; ++nt) {
            int g = (wv * 64 + nt * 16 + l16) >> 2;
            atomicAdd(&sred[g], s[nt]);
            atomicAdd(&sred[32 + g], q[nt]);
        }
        __syncthreads();
        if (t < 32) { atomicAdd(&gsum[t], sred[t]); atomicAdd(&gsq[t], sred[32 + t]); }
    }
}

// ---------------------------------------------------------------------------
extern "C" void kernel_launch(void* const* d_in, const int* in_sizes, int n_in,
                              void* d_out, int out_size, void* d_ws, size_t ws_size,
                              hipStream_t stream) {
    const float* feats  = (const float*)d_in[0];
    const float* gamma1 = (const float*)d_in[1];
    const float* beta1  = (const float*)d_in[2];
    const float* W1     = (const float*)d_in[3];
    const float* b1     = (const float*)d_in[4];
    const float* gamma2 = (const float*)d_in[5];
    const float* beta2  = (const float*)d_in[6];
    const float* W2     = (const float*)d_in[7];
    const float* b2     = (const float*)d_in[8];
    const int*   coords = (const int*)d_in[9];
    float* out = (float*)d_out;   // 65536 x 128 fp32 (written only by conv2)

    char* ws = (char*)d_ws;
    unsigned short* h0b = (unsigned short*)(ws);                    // 2 MB
    unsigned short* h1b = (unsigned short*)(ws + (2u << 20));       // 16 MB
    unsigned short* Wp1 = (unsigned short*)(ws + (18u << 20));      // 864 KB
    unsigned short* Wp2 = (unsigned short*)(ws + (19u << 20));      // 864 KB
    int*   grid32       = (int*)  (ws + (20u << 20));               // 128 KB
    float* stats        = (float*)(ws + (20u << 20) + 131072);      // 512 B
    float* zpage        = (float*)(ws + (20u << 20) + 131072 + 512);// 512 B
    int*   idx_tab      = (int*)  (ws + (21u << 20));               // 7.08 MB

    scatter_kernel<<<NPAR / 256, 256, 0, stream>>>(coords, grid32, stats, zpage);
    prep_kernel<<<688, 256, 0, stream>>>(coords, grid32, idx_tab, W1, W2, Wp1, Wp2);

    gn_stats_kernel<<<256, 256, 0, stream>>>(feats, stats + 0, stats + 32, NPAR);
    gn_apply_kernel<<<256, 256, 0, stream>>>(feats, stats + 0, stats + 32, gamma1, beta1, h0b, NPAR);

    // conv1 -> bf16 h1b (+fused GN2 stats on rounded values)
    conv_mfma_kernel<<<NCH / 64, 128, 0, stream>>>(h0b, Wp1, b1, idx_tab,
                                                   nullptr, h1b, zpage, 3, 1,
                                                   stats + 64, stats + 96);

    gn_apply_bf16_kernel<<<512, 256, 0, stream>>>(h1b, stats + 64, stats + 96, gamma2, beta2, NCH);

    // conv2 -> fp32 out + residual repeat(feats,8)
    conv_mfma_kernel<<<NCH / 64, 128, 0, stream>>>(h1b, Wp2, b2, idx_tab,
                                                   feats, out, zpage, 0, 0,
                                                   nullptr, nullptr);
}